// Round 5
// baseline (2624.025 us; speedup 1.0000x reference)
//
#include <hip/hip_runtime.h>
#include <hip/hip_bf16.h>
#include <math.h>

#define B_   16384
#define NT   10
#define KNN  5
#define D_   512
#define MTOT (B_*NT)   // 163840

typedef __bf16 bf;
typedef __bf16 bfrag8 __attribute__((ext_vector_type(8)));
typedef float  floatx4 __attribute__((ext_vector_type(4)));

__device__ __forceinline__ float tof(bf x) { return (float)x; }
__device__ __forceinline__ bf    tob(float x) { return (bf)x; }

// ---------------------------------------------------------------------------
// Swizzled LDS helpers for [80][512] bf16 tiles (row stride 1024 B).
// byte = row*1024 + (col*2 ^ ((row&7)<<4))  -- T2 XOR swizzle: A-fragment
// column reads (16 lanes, 16 different rows, same col) spread across all 32
// banks at 2-way (free, m136). 16B-aligned cols stay 16B-aligned (XOR<128,
// multiple of 16).
// ---------------------------------------------------------------------------
__device__ __forceinline__ void sw_st16(bf* lds, int row, int col, bf v) {
    *(bf*)((char*)lds + row * 1024 + ((col * 2) ^ ((row & 7) << 4))) = v;
}
__device__ __forceinline__ bf sw_ld16(const bf* lds, int row, int col) {
    return *(const bf*)((const char*)lds + row * 1024 + ((col * 2) ^ ((row & 7) << 4)));
}

// ---------------------------------------------------------------------------
// Fold kernel (f32 inputs -> bf16 folded weights):
// At_h[n,k] = (Wq_h^T Wk_h / 16)^T ; Ct_h[d,k] = (Wv_h^T Wo_h')^T
// wconst[d] = bo[d] + sum_e bv[e]*wo[d,e] ; uvec_h[k] = Wk_h^T bq_h / 16
// ---------------------------------------------------------------------------
__global__ void prep_folds(const float* __restrict__ wqkv, const float* __restrict__ bqkv,
                           const float* __restrict__ wo,   const float* __restrict__ bo,
                           bf* __restrict__ At, bf* __restrict__ Ct,
                           float* __restrict__ wconst, float* __restrict__ uvec)
{
    int gid = blockIdx.x, tid = threadIdx.x;
    if (gid < 4096) {
        int idx = gid * 256 + tid;           // 0 .. 4*262144-1
        int mat = idx >> 18;
        int rem = idx & 262143;
        int row = rem >> 9, col = rem & 511;
        float acc = 0.f;
        if (mat < 2) {
            int h = mat;
            const float* wq = wqkv + (size_t)(h * 256) * 512;
            const float* wk = wqkv + (size_t)(512 + h * 256) * 512;
            for (int c = 0; c < 256; ++c)
                acc += wq[c * 512 + col] * wk[c * 512 + row];
            At[(size_t)h * 262144 + row * 512 + col] = tob(acc * 0.0625f);
        } else {
            int h = mat - 2;
            const float* wv = wqkv + (size_t)(1024 + h * 256) * 512;
            for (int e = 0; e < 256; ++e)
                acc += wv[e * 512 + col] * wo[row * 512 + h * 256 + e];
            Ct[(size_t)h * 262144 + row * 512 + col] = tob(acc);
        }
    } else {
        for (int d = tid; d < 512; d += 256) {
            float acc = bo[d];
            for (int e = 0; e < 512; ++e)
                acc += bqkv[1024 + e] * wo[d * 512 + e];
            wconst[d] = acc;
            for (int h = 0; h < 2; ++h) {
                float u = 0.f;
                for (int c = 0; c < 256; ++c)
                    u += wqkv[(size_t)(512 + h * 256 + c) * 512 + d] * bqkv[h * 256 + c];
                uvec[h * 512 + d] = u * 0.0625f;
            }
        }
    }
}

// ---------------------------------------------------------------------------
// cvt_w: cast f32 [512,512] weight to bf16 (row-major preserved)
// ---------------------------------------------------------------------------
__global__ void cvt_w(const float* __restrict__ src, bf* __restrict__ dst)
{
    int i = blockIdx.x * 256 + threadIdx.x;     // 262144/4 threads, float4 each
    float4 v = *(const float4*)(src + (size_t)i * 4);
    bf o[4] = { tob(v.x), tob(v.y), tob(v.z), tob(v.w) };
    *(unsigned long long*)(dst + (size_t)i * 4) = *(unsigned long long*)o;
}

// ---------------------------------------------------------------------------
// rel: boxes (f32) -> per-token K-NN relative features [MTOT, 20] (f32)
// fp contract off: match numpy's round-per-op f32 so argmin ties match ref
// ---------------------------------------------------------------------------
__global__ void rel_kernel(const float* __restrict__ boxes, float* __restrict__ rel)
{
#pragma clang fp contract(off)
    int gid = blockIdx.x * blockDim.x + threadIdx.x;
    if (gid >= MTOT) return;
    int b = gid / NT, n = gid % NT;
    const float* bx = boxes + (size_t)b * NT * 4;
    float cx[NT], cy[NT], bw[NT], bh[NT];
#pragma unroll
    for (int j = 0; j < NT; ++j) {
        float x0 = bx[j * 4 + 0], y0 = bx[j * 4 + 1];
        float x1 = bx[j * 4 + 2], y1 = bx[j * 4 + 3];
        cx[j] = ((x0 + x1) * 0.5f) * (1.f / 512.f);
        cy[j] = ((y0 + y1) * 0.5f) * (1.f / 512.f);
        bw[j] = fabsf(x1 - x0) * (1.f / 512.f);
        bh[j] = fabsf(y1 - y0) * (1.f / 512.f);
    }
    float dist[NT];
#pragma unroll
    for (int j = 0; j < NT; ++j) {
        float dx = cx[n] - cx[j], dy = cy[n] - cy[j];
        float dxx = dx * dx, dyy = dy * dy;
        dist[j] = (j == n) ? __builtin_inff() : (dxx + dyy);
    }
    float ocx = cx[n], ocy = cy[n], obw = bw[n], obh = bh[n];
#pragma unroll
    for (int k = 0; k < KNN; ++k) {
        int best = 0; float bd = __builtin_inff();
#pragma unroll
        for (int j = 0; j < NT; ++j)
            if (dist[j] < bd) { bd = dist[j]; best = j; }   // strict <  == lowest-index tie-break
        float fx = 0, fy = 0, fw = 0, fh = 0;
#pragma unroll
        for (int j = 0; j < NT; ++j)
            if (j == best) { fx = cx[j]; fy = cy[j]; fw = bw[j]; fh = bh[j]; dist[j] = __builtin_inff(); }
        size_t o = (size_t)gid * 20 + k * 4;
        rel[o + 0] = fx - ocx;
        rel[o + 1] = fy - ocy;
        rel[o + 2] = fw - obw;
        rel[o + 3] = fh - obh;
    }
}

// ---------------------------------------------------------------------------
// gemm_ph: per-wave 80x64 slice of OUT[80][512] = IN_lds[80][512] @ W^T
// W row-major [512 out][512 in] (bf16, L2-resident). A from swizzled LDS
// (2-way bank, free); B via per-wave global bfrag8 loads, depth-1 prefetch
// (wave's 64 lanes cover 16 full 64B lines -> no overfetch). NO barriers.
// ---------------------------------------------------------------------------
__device__ __forceinline__ void gemm_ph(const bf* INlds, const bf* __restrict__ W,
                                        floatx4 (&acc)[5][4], int w, int lq, int lr,
                                        const int (&rb0)[5], const int (&sw0)[5])
{
    const bf* Wb = W + (size_t)(w * 64 + lr) * 512 + lq * 8;
    bfrag8 bv[4], bn[4];
#pragma unroll
    for (int j = 0; j < 4; ++j) bv[j] = *(const bfrag8*)(Wb + (size_t)j * 8192);
    for (int ks = 0; ks < 16; ++ks) {
        if (ks < 15) {
#pragma unroll
            for (int j = 0; j < 4; ++j)
                bn[j] = *(const bfrag8*)(Wb + (size_t)j * 8192 + (ks + 1) * 32);
        }
        int cb = ks * 64 + lq * 16;
        bfrag8 af[5];
#pragma unroll
        for (int i = 0; i < 5; ++i)
            af[i] = *(const bfrag8*)((const char*)INlds + (rb0[i] + (cb ^ sw0[i])));
#pragma unroll
        for (int i = 0; i < 5; ++i)
#pragma unroll
            for (int j = 0; j < 4; ++j)
                acc[i][j] = __builtin_amdgcn_mfma_f32_16x16x32_bf16(af[i], bv[j], acc[i][j], 0, 0, 0);
#pragma unroll
        for (int j = 0; j < 4; ++j) bv[j] = bn[j];
    }
}

// ---------------------------------------------------------------------------
// scores_z: per wave (batch = wave id), head h:
// S = t_b @ x_b^T + xu ; softmax ; z = att @ x_b  written into Ts rows
// (wave only touches its own 10 rows -> no barrier needed inside).
// att kept in registers, distributed a_r[r] = att[lq*4+r][lr]; z-phase
// fetches att[i][j] via __shfl (no LDS scratch).
// ---------------------------------------------------------------------------
__device__ __forceinline__ void scores_z(const bf* Xs, bf* Ts, const float* __restrict__ uvec_h,
                                         int w, int l, int lq, int lr)
{
    int rb = w * 10;
    int arow = rb + (lr < 10 ? lr : 0);     // dummy row for lr>=10, masked below
    int abase = arow * 1024, asw = (arow & 7) << 4;
    floatx4 sacc = {0.f, 0.f, 0.f, 0.f};
    float xu = 0.f;
#pragma unroll
    for (int kk = 0; kk < 16; ++kk) {
        int cb = kk * 64 + lq * 16;
        bfrag8 a  = *(const bfrag8*)((const char*)Ts + abase + (cb ^ asw));
        bfrag8 bb = *(const bfrag8*)((const char*)Xs + abase + (cb ^ asw));
        sacc = __builtin_amdgcn_mfma_f32_16x16x32_bf16(a, bb, sacc, 0, 0, 0);
#pragma unroll
        for (int jj = 0; jj < 8; ++jj)
            xu += (float)bb[jj] * uvec_h[kk * 32 + lq * 8 + jj];
    }
    xu += __shfl_xor(xu, 16);
    xu += __shfl_xor(xu, 32);               // xu for column j = lr
    bool jv = (lr < 10);
    float a_r[4];
#pragma unroll
    for (int r = 0; r < 4; ++r) {
        float v = jv ? (sacc[r] + xu) : -__builtin_inff();
        float m = v;
        m = fmaxf(m, __shfl_xor(m, 1)); m = fmaxf(m, __shfl_xor(m, 2));
        m = fmaxf(m, __shfl_xor(m, 4)); m = fmaxf(m, __shfl_xor(m, 8));
        float e = jv ? __expf(v - m) : 0.f;
        float s = e;
        s += __shfl_xor(s, 1); s += __shfl_xor(s, 2);
        s += __shfl_xor(s, 4); s += __shfl_xor(s, 8);
        a_r[r] = e / s;                     // att[lq*4+r][lr]; rows>=10 garbage, never used
    }
    // z[i][dslice(l*8)] = sum_j att[i][j] * x[rb+j][dslice]
    bfrag8 xj[10];
#pragma unroll
    for (int j = 0; j < 10; ++j) {
        int row = rb + j;
        xj[j] = *(const bfrag8*)((const char*)Xs + row * 1024 + ((l * 16) ^ ((row & 7) << 4)));
    }
#pragma unroll
    for (int i = 0; i < 10; ++i) {
        float zz[8] = {0, 0, 0, 0, 0, 0, 0, 0};
#pragma unroll
        for (int j = 0; j < 10; ++j) {
            float aij = __shfl(a_r[i & 3], ((i >> 2) << 4) + j);
#pragma unroll
            for (int q = 0; q < 8; ++q) zz[q] += aij * (float)xj[j][q];
        }
        bfrag8 zv;
#pragma unroll
        for (int q = 0; q < 8; ++q) zv[q] = tob(zz[q]);
        int row = rb + i;
        *(bfrag8*)((char*)Ts + row * 1024 + ((l * 16) ^ ((row & 7) << 4))) = zv;
    }
}

// ---------------------------------------------------------------------------
// fused: whole network after rel. One block = 8 batches = 80 tokens.
// X[80][512] + T[80][512] bf16 swizzled = exactly 160 KiB LDS, 1 block/CU,
// 8 waves (2/SIMD). Wave n-split: wave w owns cols [64w, 64w+64).
// y (attn out) accumulates in f32 registers across both heads (accY).
// LN row-stats via per-wave shfl partials + LDS scratch (aliased on dead T).
// ---------------------------------------------------------------------------
__global__ __launch_bounds__(512, 2)
void fused(const float* __restrict__ rel, const float* __restrict__ w_in,
           const float* __restrict__ b_in,
           const bf* __restrict__ At, const bf* __restrict__ Ct,
           const float* __restrict__ uvec, const float* __restrict__ wconst,
           const bf* __restrict__ W1b, const float* __restrict__ b1,
           const bf* __restrict__ W2b, const float* __restrict__ b2,
           const float* __restrict__ l1w, const float* __restrict__ l1b,
           const float* __restrict__ l2w, const float* __restrict__ l2b,
           const float* __restrict__ lfw, const float* __restrict__ lfb,
           float* __restrict__ out)
{
    __shared__ __align__(16) bf Xs[40960];   // 80 KiB
    __shared__ __align__(16) bf Ts[40960];   // 80 KiB
    int tid = threadIdx.x;
    int w = tid >> 6, l = tid & 63, lq = l >> 4, lr = l & 15;
    size_t tok0 = (size_t)blockIdx.x * 80;

    // P0: stage rel rows into T-alias
    {
        float* relS = (float*)Ts;
        for (int i = tid; i < 1600; i += 512) relS[i] = rel[tok0 * 20 + i];
    }
    __syncthreads();
    // P1: x0 = rel @ w_in^T + b_in  -> Xs (bf16, swizzled). thread = col.
    {
        const float* relS = (const float*)Ts;
        float wreg[20];
#pragma unroll
        for (int k = 0; k < 20; ++k) wreg[k] = w_in[tid * 20 + k];
        float bias = b_in[tid];
        for (int r = 0; r < 80; ++r) {
            float a = bias;
#pragma unroll
            for (int k = 0; k < 20; ++k) a += relS[r * 20 + k] * wreg[k];
            sw_st16(Xs, r, tid, tob(a));
        }
    }
    __syncthreads();

    floatx4 acc[5][4];
    floatx4 accY[5][4];
    float   mus[5][4];
    int rb0[5], sw0[5];
#pragma unroll
    for (int i = 0; i < 5; ++i) { int row = i * 16 + lr; rb0[i] = row * 1024; sw0[i] = (row & 7) << 4; }

    // ---- attention, both heads; y accumulates in accY (f32, never leaves regs)
    for (int h = 0; h < 2; ++h) {
        // t = x0 @ At_h -> Ts
#pragma unroll
        for (int i = 0; i < 5; ++i)
#pragma unroll
            for (int j = 0; j < 4; ++j) acc[i][j] = (floatx4){0.f, 0.f, 0.f, 0.f};
        gemm_ph(Xs, At + (size_t)h * 262144, acc, w, lq, lr, rb0, sw0);
#pragma unroll
        for (int i = 0; i < 5; ++i)
#pragma unroll
            for (int j = 0; j < 4; ++j) {
                int col = w * 64 + j * 16 + lr;
#pragma unroll
                for (int r = 0; r < 4; ++r)
                    sw_st16(Ts, i * 16 + lq * 4 + r, col, tob(acc[i][j][r]));
            }
        __syncthreads();
        // scores + softmax + z (z overwrites Ts rows of own batch only)
        scores_z(Xs, Ts, uvec + h * 512, w, l, lq, lr);
        __syncthreads();
        if (h == 0) {
#pragma unroll
            for (int j = 0; j < 4; ++j) {
                float wc = wconst[w * 64 + j * 16 + lr];
#pragma unroll
                for (int i = 0; i < 5; ++i) accY[i][j] = (floatx4){wc, wc, wc, wc};
            }
        }
        // y += z @ Ct_h
        gemm_ph(Ts, Ct + (size_t)h * 262144, accY, w, lq, lr, rb0, sw0);
        __syncthreads();
    }

    // ---- P8: x1 = LN1(x0 + y) -> Xs  (exact two-pass; scratch aliases dead Ts)
    {
        float* scr  = (float*)Ts;
        float* scr2 = scr + 640;
        float lnw[4], lnb[4];
#pragma unroll
        for (int j = 0; j < 4; ++j) { lnw[j] = l1w[w * 64 + j * 16 + lr]; lnb[j] = l1b[w * 64 + j * 16 + lr]; }
#pragma unroll
        for (int i = 0; i < 5; ++i)
#pragma unroll
            for (int r = 0; r < 4; ++r) {
                int row = i * 16 + lq * 4 + r;
                float ps = 0.f;
#pragma unroll
                for (int j = 0; j < 4; ++j) {
                    int col = w * 64 + j * 16 + lr;
                    float v = accY[i][j][r] + tof(sw_ld16(Xs, row, col));
                    accY[i][j][r] = v;
                    ps += v;
                }
                ps += __shfl_xor(ps, 1); ps += __shfl_xor(ps, 2);
                ps += __shfl_xor(ps, 4); ps += __shfl_xor(ps, 8);
                if (lr == 0) scr[row * 8 + w] = ps;
            }
        __syncthreads();
#pragma unroll
        for (int i = 0; i < 5; ++i)
#pragma unroll
            for (int r = 0; r < 4; ++r) {
                int row = i * 16 + lq * 4 + r;
                float s = 0.f;
#pragma unroll
                for (int q = 0; q < 8; ++q) s += scr[row * 8 + q];
                float mu = s * (1.f / 512.f);
                mus[i][r] = mu;
                float ps2 = 0.f;
#pragma unroll
                for (int j = 0; j < 4; ++j) { float d = accY[i][j][r] - mu; ps2 += d * d; }
                ps2 += __shfl_xor(ps2, 1); ps2 += __shfl_xor(ps2, 2);
                ps2 += __shfl_xor(ps2, 4); ps2 += __shfl_xor(ps2, 8);
                if (lr == 0) scr2[row * 8 + w] = ps2;
            }
        __syncthreads();
#pragma unroll
        for (int i = 0; i < 5; ++i)
#pragma unroll
            for (int r = 0; r < 4; ++r) {
                int row = i * 16 + lq * 4 + r;
                float s2 = 0.f;
#pragma unroll
                for (int q = 0; q < 8; ++q) s2 += scr2[row * 8 + q];
                float rstd = rsqrtf(s2 * (1.f / 512.f) + 1e-5f);
#pragma unroll
                for (int j = 0; j < 4; ++j) {
                    int col = w * 64 + j * 16 + lr;
                    sw_st16(Xs, row, col, tob((accY[i][j][r] - mus[i][r]) * rstd * lnw[j] + lnb[j]));
                }
            }
        __syncthreads();
    }

    // ---- P9: ff1 = gelu(x1 @ W1 + b1) -> Ts
    {
#pragma unroll
        for (int i = 0; i < 5; ++i)
#pragma unroll
            for (int j = 0; j < 4; ++j) acc[i][j] = (floatx4){0.f, 0.f, 0.f, 0.f};
        gemm_ph(Xs, W1b, acc, w, lq, lr, rb0, sw0);
        float b1c[4];
#pragma unroll
        for (int j = 0; j < 4; ++j) b1c[j] = b1[w * 64 + j * 16 + lr];
#pragma unroll
        for (int i = 0; i < 5; ++i)
#pragma unroll
            for (int j = 0; j < 4; ++j) {
                int col = w * 64 + j * 16 + lr;
#pragma unroll
                for (int r = 0; r < 4; ++r) {
                    float v = acc[i][j][r] + b1c[j];
                    v = 0.5f * v * (1.f + erff(v * 0.70710678118654752f));
                    sw_st16(Ts, i * 16 + lq * 4 + r, col, tob(v));
                }
            }
        __syncthreads();
    }

    // ---- P10: ff2 = ff1 @ W2 (b2 added in P11) -> acc (f32 regs)
    {
#pragma unroll
        for (int i = 0; i < 5; ++i)
#pragma unroll
            for (int j = 0; j < 4; ++j) acc[i][j] = (floatx4){0.f, 0.f, 0.f, 0.f};
        gemm_ph(Ts, W2b, acc, w, lq, lr, rb0, sw0);
        __syncthreads();   // all Ts (ff1) reads done before scratch aliasing
    }

    // ---- P11: out = LNF( LN2(x1 + ff2 + b2) ) -> global f32
    {
        float* scr  = (float*)Ts;
        float* scr2 = scr + 640;
        float b2c[4], w2c[4], bb2[4], wfc[4], bfc[4];
#pragma unroll
        for (int j = 0; j < 4; ++j) {
            int col = w * 64 + j * 16 + lr;
            b2c[j] = b2[col]; w2c[j] = l2w[col]; bb2[j] = l2b[col];
            wfc[j] = lfw[col]; bfc[j] = lfb[col];
        }
        // pass 1: v2 = x1 + ff2 + b2 ; row sums
#pragma unroll
        for (int i = 0; i < 5; ++i)
#pragma unroll
            for (int r = 0; r < 4; ++r) {
                int row = i * 16 + lq * 4 + r;
                float ps = 0.f;
#pragma unroll
                for (int j = 0; j < 4; ++j) {
                    int col = w * 64 + j * 16 + lr;
                    float v = acc[i][j][r] + tof(sw_ld16(Xs, row, col)) + b2c[j];
                    acc[i][j][r] = v;
                    ps += v;
                }
                ps += __shfl_xor(ps, 1); ps += __shfl_xor(ps, 2);
                ps += __shfl_xor(ps, 4); ps += __shfl_xor(ps, 8);
                if (lr == 0) scr[row * 8 + w] = ps;
            }
        __syncthreads();
        // pass 2: mu2 ; sumsq
#pragma unroll
        for (int i = 0; i < 5; ++i)
#pragma unroll
            for (int r = 0; r < 4; ++r) {
                int row = i * 16 + lq * 4 + r;
                float s = 0.f;
#pragma unroll
                for (int q = 0; q < 8; ++q) s += scr[row * 8 + q];
                float mu = s * (1.f / 512.f);
                mus[i][r] = mu;
                float ps2 = 0.f;
#pragma unroll
                for (int j = 0; j < 4; ++j) { float d = acc[i][j][r] - mu; ps2 += d * d; }
                ps2 += __shfl_xor(ps2, 1); ps2 += __shfl_xor(ps2, 2);
                ps2 += __shfl_xor(ps2, 4); ps2 += __shfl_xor(ps2, 8);
                if (lr == 0) scr2[row * 8 + w] = ps2;
            }
        __syncthreads();
        // pass 3: u = LN2(v2) ; u row sums (overwrite scr: all scr reads done)
#pragma unroll
        for (int i = 0; i < 5; ++i)
#pragma unroll
            for (int r = 0; r < 4; ++r) {
                int row = i * 16 + lq * 4 + r;
                float s2 = 0.f;
#pragma unroll
                for (int q = 0; q < 8; ++q) s2 += scr2[row * 8 + q];
                float rstd = rsqrtf(s2 * (1.f / 512.f) + 1e-5f);
                float ps = 0.f;
#pragma unroll
                for (int j = 0; j < 4; ++j) {
                    float u = (acc[i][j][r] - mus[i][r]) * rstd * w2c[j] + bb2[j];
                    acc[i][j][r] = u;
                    ps += u;
                }
                ps += __shfl_xor(ps, 1); ps += __shfl_xor(ps, 2);
                ps += __shfl_xor(ps, 4); ps += __shfl_xor(ps, 8);
                if (lr == 0) scr[row * 8 + w] = ps;
            }
        __syncthreads();
        // pass 4: mu3 ; u sumsq
#pragma unroll
        for (int i = 0; i < 5; ++i)
#pragma unroll
            for (int r = 0; r < 4; ++r) {
                int row = i * 16 + lq * 4 + r;
                float s = 0.f;
#pragma unroll
                for (int q = 0; q < 8; ++q) s += scr[row * 8 + q];
                float mu = s * (1.f / 512.f);
                mus[i][r] = mu;
                float ps2 = 0.f;
#pragma unroll
                for (int j = 0; j < 4; ++j) { float d = acc[i][j][r] - mu; ps2 += d * d; }
                ps2 += __shfl_xor(ps2, 1); ps2 += __shfl_xor(ps2, 2);
                ps2 += __shfl_xor(ps2, 4); ps2 += __shfl_xor(ps2, 8);
                if (lr == 0) scr2[row * 8 + w] = ps2;
            }
        __syncthreads();
        // pass 5: out = LNF(u)
#pragma unroll
        for (int i = 0; i < 5; ++i)
#pragma unroll
            for (int r = 0; r < 4; ++r) {
                int row = i * 16 + lq * 4 + r;
                float s2 = 0.f;
#pragma unroll
                for (int q = 0; q < 8; ++q) s2 += scr2[row * 8 + q];
                float rstd = rsqrtf(s2 * (1.f / 512.f) + 1e-5f);
#pragma unroll
                for (int j = 0; j < 4; ++j) {
                    int col = w * 64 + j * 16 + lr;
                    out[(tok0 + row) * 512 + col] =
                        (acc[i][j][r] - mus[i][r]) * rstd * wfc[j] + bfc[j];
                }
            }
    }
}

// ---------------------------------------------------------------------------
extern "C" void kernel_launch(void* const* d_in, const int* in_sizes, int n_in,
                              void* d_out, int out_size, void* d_ws, size_t ws_size,
                              hipStream_t stream)
{
    const float* boxes = (const float*)d_in[0];
    const float* w_in  = (const float*)d_in[1];
    const float* b_in  = (const float*)d_in[2];
    const float* wqkv  = (const float*)d_in[3];
    const float* bqkv  = (const float*)d_in[4];
    const float* wo    = (const float*)d_in[5];
    const float* bo    = (const float*)d_in[6];
    const float* ln1w  = (const float*)d_in[7];
    const float* ln1b  = (const float*)d_in[8];
    const float* w1    = (const float*)d_in[9];
    const float* b1    = (const float*)d_in[10];
    const float* w2    = (const float*)d_in[11];
    const float* b2    = (const float*)d_in[12];
    const float* ln2w  = (const float*)d_in[13];
    const float* ln2b  = (const float*)d_in[14];
    const float* lnfw  = (const float*)d_in[15];
    const float* lnfb  = (const float*)d_in[16];
    float* out = (float*)d_out;

    char* ws = (char*)d_ws;
    // layout (bytes), total ~16.3 MB:
    bf*    At     = (bf*)(ws + 0);                            //  1,048,576
    bf*    Ct     = (bf*)(ws + 1048576);                      //  1,048,576
    bf*    W1b    = (bf*)(ws + 2097152);                      //  524,288
    bf*    W2b    = (bf*)(ws + 2621440);                      //  524,288
    float* wconst = (float*)(ws + 3145728);                   //  2,048
    float* uvec   = (float*)(ws + 3147776);                   //  4,096
    float* rel    = (float*)(ws + 3151872);                   //  13,107,200

    dim3 gblk(256);

    prep_folds<<<4097, gblk, 0, stream>>>(wqkv, bqkv, wo, bo, At, Ct, wconst, uvec);
    cvt_w<<<256, gblk, 0, stream>>>(w1, W1b);
    cvt_w<<<256, gblk, 0, stream>>>(w2, W2b);
    rel_kernel<<<(MTOT + 255) / 256, gblk, 0, stream>>>(boxes, rel);

    fused<<<MTOT / 80, 512, 0, stream>>>(rel, w_in, b_in, At, Ct, uvec, wconst,
                                         W1b, b1, W2b, b2,
                                         ln1w, ln1b, ln2w, ln2b, lnfw, lnfb, out);
}

// Round 6
// 2088.033 us; speedup vs baseline: 1.2567x; 1.2567x over previous
//
#include <hip/hip_runtime.h>
#include <hip/hip_bf16.h>
#include <math.h>

#define B_   16384
#define NT   10
#define KNN  5
#define D_   512
#define MTOT (B_*NT)   // 163840

typedef __bf16 bf;
typedef __bf16 bfrag8 __attribute__((ext_vector_type(8)));
typedef float  floatx4 __attribute__((ext_vector_type(4)));

__device__ __forceinline__ float tof(bf x) { return (float)x; }
__device__ __forceinline__ bf    tob(float x) { return (bf)x; }

// ---------------------------------------------------------------------------
// Swizzled LDS helpers for [80][512] bf16 tiles (row stride 1024 B).
// byte = row*1024 + (col*2 ^ ((row&7)<<4))  -- T2 XOR swizzle.
// ---------------------------------------------------------------------------
__device__ __forceinline__ void sw_st16(bf* lds, int row, int col, bf v) {
    *(bf*)((char*)lds + row * 1024 + ((col * 2) ^ ((row & 7) << 4))) = v;
}
__device__ __forceinline__ bf sw_ld16(const bf* lds, int row, int col) {
    return *(const bf*)((const char*)lds + row * 1024 + ((col * 2) ^ ((row & 7) << 4)));
}

// ---------------------------------------------------------------------------
// prep_folds / cvt_w / rel_kernel unchanged (verified)
// ---------------------------------------------------------------------------
__global__ void prep_folds(const float* __restrict__ wqkv, const float* __restrict__ bqkv,
                           const float* __restrict__ wo,   const float* __restrict__ bo,
                           bf* __restrict__ At, bf* __restrict__ Ct,
                           float* __restrict__ wconst, float* __restrict__ uvec)
{
    int gid = blockIdx.x, tid = threadIdx.x;
    if (gid < 4096) {
        int idx = gid * 256 + tid;
        int mat = idx >> 18;
        int rem = idx & 262143;
        int row = rem >> 9, col = rem & 511;
        float acc = 0.f;
        if (mat < 2) {
            int h = mat;
            const float* wq = wqkv + (size_t)(h * 256) * 512;
            const float* wk = wqkv + (size_t)(512 + h * 256) * 512;
            for (int c = 0; c < 256; ++c)
                acc += wq[c * 512 + col] * wk[c * 512 + row];
            At[(size_t)h * 262144 + row * 512 + col] = tob(acc * 0.0625f);
        } else {
            int h = mat - 2;
            const float* wv = wqkv + (size_t)(1024 + h * 256) * 512;
            for (int e = 0; e < 256; ++e)
                acc += wv[e * 512 + col] * wo[row * 512 + h * 256 + e];
            Ct[(size_t)h * 262144 + row * 512 + col] = tob(acc);
        }
    } else {
        for (int d = tid; d < 512; d += 256) {
            float acc = bo[d];
            for (int e = 0; e < 512; ++e)
                acc += bqkv[1024 + e] * wo[d * 512 + e];
            wconst[d] = acc;
            for (int h = 0; h < 2; ++h) {
                float u = 0.f;
                for (int c = 0; c < 256; ++c)
                    u += wqkv[(size_t)(512 + h * 256 + c) * 512 + d] * bqkv[h * 256 + c];
                uvec[h * 512 + d] = u * 0.0625f;
            }
        }
    }
}

__global__ void cvt_w(const float* __restrict__ src, bf* __restrict__ dst)
{
    int i = blockIdx.x * 256 + threadIdx.x;
    float4 v = *(const float4*)(src + (size_t)i * 4);
    bf o[4] = { tob(v.x), tob(v.y), tob(v.z), tob(v.w) };
    *(unsigned long long*)(dst + (size_t)i * 4) = *(unsigned long long*)o;
}

__global__ void rel_kernel(const float* __restrict__ boxes, float* __restrict__ rel)
{
#pragma clang fp contract(off)
    int gid = blockIdx.x * blockDim.x + threadIdx.x;
    if (gid >= MTOT) return;
    int b = gid / NT, n = gid % NT;
    const float* bx = boxes + (size_t)b * NT * 4;
    float cx[NT], cy[NT], bw[NT], bh[NT];
#pragma unroll
    for (int j = 0; j < NT; ++j) {
        float x0 = bx[j * 4 + 0], y0 = bx[j * 4 + 1];
        float x1 = bx[j * 4 + 2], y1 = bx[j * 4 + 3];
        cx[j] = ((x0 + x1) * 0.5f) * (1.f / 512.f);
        cy[j] = ((y0 + y1) * 0.5f) * (1.f / 512.f);
        bw[j] = fabsf(x1 - x0) * (1.f / 512.f);
        bh[j] = fabsf(y1 - y0) * (1.f / 512.f);
    }
    float dist[NT];
#pragma unroll
    for (int j = 0; j < NT; ++j) {
        float dx = cx[n] - cx[j], dy = cy[n] - cy[j];
        float dxx = dx * dx, dyy = dy * dy;
        dist[j] = (j == n) ? __builtin_inff() : (dxx + dyy);
    }
    float ocx = cx[n], ocy = cy[n], obw = bw[n], obh = bh[n];
#pragma unroll
    for (int k = 0; k < KNN; ++k) {
        int best = 0; float bd = __builtin_inff();
#pragma unroll
        for (int j = 0; j < NT; ++j)
            if (dist[j] < bd) { bd = dist[j]; best = j; }
        float fx = 0, fy = 0, fw = 0, fh = 0;
#pragma unroll
        for (int j = 0; j < NT; ++j)
            if (j == best) { fx = cx[j]; fy = cy[j]; fw = bw[j]; fh = bh[j]; dist[j] = __builtin_inff(); }
        size_t o = (size_t)gid * 20 + k * 4;
        rel[o + 0] = fx - ocx;
        rel[o + 1] = fy - ocy;
        rel[o + 2] = fw - obw;
        rel[o + 3] = fh - obh;
    }
}

// ---------------------------------------------------------------------------
// gemm_ph: per-wave 80x64 slice of OUT[80][512] = IN_lds[80][512] @ W^T.
// A from swizzled LDS; B (weights, L2-resident) via bfrag8 loads, depth-1
// prefetch. NO barriers inside. Accumulates into caller's acc (80 VGPR).
// ---------------------------------------------------------------------------
__device__ __forceinline__ void gemm_ph(const bf* INlds, const bf* __restrict__ W,
                                        floatx4 (&acc)[5][4], int w, int lq, int lr,
                                        const int (&rb0)[5], const int (&sw0)[5])
{
    const bf* Wb = W + (size_t)(w * 64 + lr) * 512 + lq * 8;
    bfrag8 bv[4], bn[4];
#pragma unroll
    for (int j = 0; j < 4; ++j) bv[j] = *(const bfrag8*)(Wb + (size_t)j * 8192);
    for (int ks = 0; ks < 16; ++ks) {
        if (ks < 15) {
#pragma unroll
            for (int j = 0; j < 4; ++j)
                bn[j] = *(const bfrag8*)(Wb + (size_t)j * 8192 + (ks + 1) * 32);
        }
        int cb = ks * 64 + lq * 16;
        bfrag8 af[5];
#pragma unroll
        for (int i = 0; i < 5; ++i)
            af[i] = *(const bfrag8*)((const char*)INlds + (rb0[i] + (cb ^ sw0[i])));
#pragma unroll
        for (int i = 0; i < 5; ++i)
#pragma unroll
            for (int j = 0; j < 4; ++j)
                acc[i][j] = __builtin_amdgcn_mfma_f32_16x16x32_bf16(af[i], bv[j], acc[i][j], 0, 0, 0);
#pragma unroll
        for (int j = 0; j < 4; ++j) bv[j] = bn[j];
    }
}

// C-write of a gemm result into a swizzled bf16 LDS tile
__device__ __forceinline__ void cwrite(bf* Ts, const floatx4 (&acc)[5][4], int w, int lq, int lr)
{
#pragma unroll
    for (int i = 0; i < 5; ++i)
#pragma unroll
        for (int j = 0; j < 4; ++j) {
            int col = w * 64 + j * 16 + lr;
#pragma unroll
            for (int r = 0; r < 4; ++r)
                sw_st16(Ts, i * 16 + lq * 4 + r, col, tob(acc[i][j][r]));
        }
}

// ---------------------------------------------------------------------------
// scores_only: per wave (batch = wave id): S = t_b @ x_b^T + xu; softmax.
// Result distributed in registers: a_r[r] = att[lq*4+r][lr]. Reads only the
// wave's own 10 rows of Ts/Xs.
// ---------------------------------------------------------------------------
__device__ __forceinline__ void scores_only(const bf* Xs, const bf* Ts,
                                            const float* __restrict__ uvec_h,
                                            int w, int lq, int lr, float (&a_r)[4])
{
    int rb = w * 10;
    int arow = rb + (lr < 10 ? lr : 0);
    int abase = arow * 1024, asw = (arow & 7) << 4;
    floatx4 sacc = {0.f, 0.f, 0.f, 0.f};
    float xu = 0.f;
#pragma unroll
    for (int kk = 0; kk < 16; ++kk) {
        int cb = kk * 64 + lq * 16;
        bfrag8 a  = *(const bfrag8*)((const char*)Ts + abase + (cb ^ asw));
        bfrag8 bb = *(const bfrag8*)((const char*)Xs + abase + (cb ^ asw));
        sacc = __builtin_amdgcn_mfma_f32_16x16x32_bf16(a, bb, sacc, 0, 0, 0);
#pragma unroll
        for (int jj = 0; jj < 8; ++jj)
            xu += (float)bb[jj] * uvec_h[kk * 32 + lq * 8 + jj];
    }
    xu += __shfl_xor(xu, 16);
    xu += __shfl_xor(xu, 32);
    bool jv = (lr < 10);
#pragma unroll
    for (int r = 0; r < 4; ++r) {
        float v = jv ? (sacc[r] + xu) : -__builtin_inff();
        float m = v;
        m = fmaxf(m, __shfl_xor(m, 1)); m = fmaxf(m, __shfl_xor(m, 2));
        m = fmaxf(m, __shfl_xor(m, 4)); m = fmaxf(m, __shfl_xor(m, 8));
        float e = jv ? __expf(v - m) : 0.f;
        float s = e;
        s += __shfl_xor(s, 1); s += __shfl_xor(s, 2);
        s += __shfl_xor(s, 4); s += __shfl_xor(s, 8);
        a_r[r] = e / s;
    }
}

// ---------------------------------------------------------------------------
// z_write: z = att @ x_b, written into the wave's own 10 rows of Ts.
// att[i][j] fetched from registers via __shfl.
// ---------------------------------------------------------------------------
__device__ __forceinline__ void z_write(const bf* Xs, bf* Ts, const float (&a_r)[4],
                                        int w, int l)
{
    int rb = w * 10;
    bfrag8 xj[10];
#pragma unroll
    for (int j = 0; j < 10; ++j) {
        int row = rb + j;
        xj[j] = *(const bfrag8*)((const char*)Xs + row * 1024 + ((l * 16) ^ ((row & 7) << 4)));
    }
#pragma unroll
    for (int i = 0; i < 10; ++i) {
        float zz[8] = {0, 0, 0, 0, 0, 0, 0, 0};
#pragma unroll
        for (int j = 0; j < 10; ++j) {
            float aij = __shfl(a_r[i & 3], ((i >> 2) << 4) + j);
#pragma unroll
            for (int q = 0; q < 8; ++q) zz[q] += aij * (float)xj[j][q];
        }
        bfrag8 zv;
#pragma unroll
        for (int q = 0; q < 8; ++q) zv[q] = tob(zz[q]);
        int row = rb + i;
        *(bfrag8*)((char*)Ts + row * 1024 + ((l * 16) ^ ((row & 7) << 4))) = zv;
    }
}

// ---------------------------------------------------------------------------
// fused: whole network after rel. One block = 8 batches = 80 tokens.
// X[80][512] + T[80][512] bf16 swizzled = 160 KiB LDS, 1 block/CU, 8 waves.
// SINGLE accumulator array `acc` (80 VGPR) time-shared across ALL phases --
// round-5's dual acc+accY (160 VGPR) overflowed the 256-reg residency cap
// and spilled ~2 GB to scratch. Order: t0,att0,t1,att1,z0,y0,z1,y1,LN1,
// ff1,ff2,LN2+LNF. att kept in 4 regs/lane per head.
// ---------------------------------------------------------------------------
__global__ __launch_bounds__(512, 2)
void fused(const float* __restrict__ rel, const float* __restrict__ w_in,
           const float* __restrict__ b_in,
           const bf* __restrict__ At, const bf* __restrict__ Ct,
           const float* __restrict__ uvec, const float* __restrict__ wconst,
           const bf* __restrict__ W1b, const float* __restrict__ b1,
           const bf* __restrict__ W2b, const float* __restrict__ b2,
           const float* __restrict__ l1w, const float* __restrict__ l1b,
           const float* __restrict__ l2w, const float* __restrict__ l2b,
           const float* __restrict__ lfw, const float* __restrict__ lfb,
           float* __restrict__ out)
{
    __shared__ __align__(16) bf Xs[40960];   // 80 KiB
    __shared__ __align__(16) bf Ts[40960];   // 80 KiB
    int tid = threadIdx.x;
    int w = tid >> 6, l = tid & 63, lq = l >> 4, lr = l & 15;
    size_t tok0 = (size_t)blockIdx.x * 80;

    // P0: stage rel rows into T-alias
    {
        float* relS = (float*)Ts;
        for (int i = tid; i < 1600; i += 512) relS[i] = rel[tok0 * 20 + i];
    }
    __syncthreads();
    // P1: x0 = rel @ w_in^T + b_in  -> Xs (bf16, swizzled). thread = col.
    {
        const float* relS = (const float*)Ts;
        float wreg[20];
#pragma unroll
        for (int k = 0; k < 20; ++k) wreg[k] = w_in[tid * 20 + k];
        float bias = b_in[tid];
        for (int r = 0; r < 80; ++r) {
            float a = bias;
#pragma unroll
            for (int k = 0; k < 20; ++k) a += relS[r * 20 + k] * wreg[k];
            sw_st16(Xs, r, tid, tob(a));
        }
    }
    __syncthreads();

    floatx4 acc[5][4];
    float   mus[5][4];
    float   a0[4], a1[4];
    int rb0[5], sw0[5];
#pragma unroll
    for (int i = 0; i < 5; ++i) { int row = i * 16 + lr; rb0[i] = row * 1024; sw0[i] = (row & 7) << 4; }

    // ---- t0 = x0 @ At0 -> Ts ; att0 -> regs
#pragma unroll
    for (int i = 0; i < 5; ++i)
#pragma unroll
        for (int j = 0; j < 4; ++j) acc[i][j] = (floatx4){0.f, 0.f, 0.f, 0.f};
    gemm_ph(Xs, At, acc, w, lq, lr, rb0, sw0);
    cwrite(Ts, acc, w, lq, lr);
    __syncthreads();
    scores_only(Xs, Ts, uvec, w, lq, lr, a0);
    __syncthreads();                       // att0 reads done before t1 overwrites Ts

    // ---- t1 = x0 @ At1 -> Ts ; att1 -> regs
#pragma unroll
    for (int i = 0; i < 5; ++i)
#pragma unroll
        for (int j = 0; j < 4; ++j) acc[i][j] = (floatx4){0.f, 0.f, 0.f, 0.f};
    gemm_ph(Xs, At + 262144, acc, w, lq, lr, rb0, sw0);
    cwrite(Ts, acc, w, lq, lr);
    __syncthreads();
    scores_only(Xs, Ts, uvec + 512, w, lq, lr, a1);
    // no barrier: z0 writes only this wave's own rows, att1 read only own rows
    z_write(Xs, Ts, a0, w, l);
    __syncthreads();                       // all z0 rows in place

    // ---- y = wconst + z0 @ Ct0 + z1 @ Ct1 (single acc, f32, never leaves regs)
#pragma unroll
    for (int j = 0; j < 4; ++j) {
        float wc = wconst[w * 64 + j * 16 + lr];
#pragma unroll
        for (int i = 0; i < 5; ++i) acc[i][j] = (floatx4){wc, wc, wc, wc};
    }
    gemm_ph(Ts, Ct, acc, w, lq, lr, rb0, sw0);
    __syncthreads();                       // y0 reads done before z1 overwrites Ts
    z_write(Xs, Ts, a1, w, l);
    __syncthreads();                       // all z1 rows in place
    gemm_ph(Ts, Ct + 262144, acc, w, lq, lr, rb0, sw0);
    __syncthreads();                       // y1 Ts reads done before scr aliasing

    // ---- LN1: x1 = LN1(x0 + y) -> Xs (exact two-pass; scratch aliases dead Ts)
    {
        float* scr  = (float*)Ts;
        float* scr2 = scr + 640;
        float lnw[4], lnb[4];
#pragma unroll
        for (int j = 0; j < 4; ++j) { lnw[j] = l1w[w * 64 + j * 16 + lr]; lnb[j] = l1b[w * 64 + j * 16 + lr]; }
#pragma unroll
        for (int i = 0; i < 5; ++i)
#pragma unroll
            for (int r = 0; r < 4; ++r) {
                int row = i * 16 + lq * 4 + r;
                float ps = 0.f;
#pragma unroll
                for (int j = 0; j < 4; ++j) {
                    int col = w * 64 + j * 16 + lr;
                    float v = acc[i][j][r] + tof(sw_ld16(Xs, row, col));
                    acc[i][j][r] = v;
                    ps += v;
                }
                ps += __shfl_xor(ps, 1); ps += __shfl_xor(ps, 2);
                ps += __shfl_xor(ps, 4); ps += __shfl_xor(ps, 8);
                if (lr == 0) scr[row * 8 + w] = ps;
            }
        __syncthreads();
#pragma unroll
        for (int i = 0; i < 5; ++i)
#pragma unroll
            for (int r = 0; r < 4; ++r) {
                int row = i * 16 + lq * 4 + r;
                float s = 0.f;
#pragma unroll
                for (int q = 0; q < 8; ++q) s += scr[row * 8 + q];
                float mu = s * (1.f / 512.f);
                mus[i][r] = mu;
                float ps2 = 0.f;
#pragma unroll
                for (int j = 0; j < 4; ++j) { float d = acc[i][j][r] - mu; ps2 += d * d; }
                ps2 += __shfl_xor(ps2, 1); ps2 += __shfl_xor(ps2, 2);
                ps2 += __shfl_xor(ps2, 4); ps2 += __shfl_xor(ps2, 8);
                if (lr == 0) scr2[row * 8 + w] = ps2;
            }
        __syncthreads();
#pragma unroll
        for (int i = 0; i < 5; ++i)
#pragma unroll
            for (int r = 0; r < 4; ++r) {
                int row = i * 16 + lq * 4 + r;
                float s2 = 0.f;
#pragma unroll
                for (int q = 0; q < 8; ++q) s2 += scr2[row * 8 + q];
                float rstd = rsqrtf(s2 * (1.f / 512.f) + 1e-5f);
#pragma unroll
                for (int j = 0; j < 4; ++j) {
                    int col = w * 64 + j * 16 + lr;
                    sw_st16(Xs, row, col, tob((acc[i][j][r] - mus[i][r]) * rstd * lnw[j] + lnb[j]));
                }
            }
        __syncthreads();
    }

    // ---- ff1 = gelu(x1 @ W1 + b1) -> Ts
    {
#pragma unroll
        for (int i = 0; i < 5; ++i)
#pragma unroll
            for (int j = 0; j < 4; ++j) acc[i][j] = (floatx4){0.f, 0.f, 0.f, 0.f};
        gemm_ph(Xs, W1b, acc, w, lq, lr, rb0, sw0);
        float b1c[4];
#pragma unroll
        for (int j = 0; j < 4; ++j) b1c[j] = b1[w * 64 + j * 16 + lr];
#pragma unroll
        for (int i = 0; i < 5; ++i)
#pragma unroll
            for (int j = 0; j < 4; ++j) {
                int col = w * 64 + j * 16 + lr;
#pragma unroll
                for (int r = 0; r < 4; ++r) {
                    float v = acc[i][j][r] + b1c[j];
                    v = 0.5f * v * (1.f + erff(v * 0.70710678118654752f));
                    sw_st16(Ts, i * 16 + lq * 4 + r, col, tob(v));
                }
            }
        __syncthreads();
    }

    // ---- ff2 = ff1 @ W2 -> acc (b2 added below)
    {
#pragma unroll
        for (int i = 0; i < 5; ++i)
#pragma unroll
            for (int j = 0; j < 4; ++j) acc[i][j] = (floatx4){0.f, 0.f, 0.f, 0.f};
        gemm_ph(Ts, W2b, acc, w, lq, lr, rb0, sw0);
        __syncthreads();   // all Ts (ff1) reads done before scratch aliasing
    }

    // ---- out = LNF( LN2(x1 + ff2 + b2) ) -> global f32
    {
        float* scr  = (float*)Ts;
        float* scr2 = scr + 640;
        float b2c[4], w2c[4], bb2[4], wfc[4], bfc[4];
#pragma unroll
        for (int j = 0; j < 4; ++j) {
            int col = w * 64 + j * 16 + lr;
            b2c[j] = b2[col]; w2c[j] = l2w[col]; bb2[j] = l2b[col];
            wfc[j] = lfw[col]; bfc[j] = lfb[col];
        }
        // pass 1: v2 = x1 + ff2 + b2 ; row sums
#pragma unroll
        for (int i = 0; i < 5; ++i)
#pragma unroll
            for (int r = 0; r < 4; ++r) {
                int row = i * 16 + lq * 4 + r;
                float ps = 0.f;
#pragma unroll
                for (int j = 0; j < 4; ++j) {
                    int col = w * 64 + j * 16 + lr;
                    float v = acc[i][j][r] + tof(sw_ld16(Xs, row, col)) + b2c[j];
                    acc[i][j][r] = v;
                    ps += v;
                }
                ps += __shfl_xor(ps, 1); ps += __shfl_xor(ps, 2);
                ps += __shfl_xor(ps, 4); ps += __shfl_xor(ps, 8);
                if (lr == 0) scr[row * 8 + w] = ps;
            }
        __syncthreads();
        // pass 2: mu2 ; sumsq
#pragma unroll
        for (int i = 0; i < 5; ++i)
#pragma unroll
            for (int r = 0; r < 4; ++r) {
                int row = i * 16 + lq * 4 + r;
                float s = 0.f;
#pragma unroll
                for (int q = 0; q < 8; ++q) s += scr[row * 8 + q];
                float mu = s * (1.f / 512.f);
                mus[i][r] = mu;
                float ps2 = 0.f;
#pragma unroll
                for (int j = 0; j < 4; ++j) { float d = acc[i][j][r] - mu; ps2 += d * d; }
                ps2 += __shfl_xor(ps2, 1); ps2 += __shfl_xor(ps2, 2);
                ps2 += __shfl_xor(ps2, 4); ps2 += __shfl_xor(ps2, 8);
                if (lr == 0) scr2[row * 8 + w] = ps2;
            }
        __syncthreads();
        // pass 3: u = LN2(v2) ; u row sums
#pragma unroll
        for (int i = 0; i < 5; ++i)
#pragma unroll
            for (int r = 0; r < 4; ++r) {
                int row = i * 16 + lq * 4 + r;
                float s2 = 0.f;
#pragma unroll
                for (int q = 0; q < 8; ++q) s2 += scr2[row * 8 + q];
                float rstd = rsqrtf(s2 * (1.f / 512.f) + 1e-5f);
                float ps = 0.f;
#pragma unroll
                for (int j = 0; j < 4; ++j) {
                    float u = (acc[i][j][r] - mus[i][r]) * rstd * w2c[j] + bb2[j];
                    acc[i][j][r] = u;
                    ps += u;
                }
                ps += __shfl_xor(ps, 1); ps += __shfl_xor(ps, 2);
                ps += __shfl_xor(ps, 4); ps += __shfl_xor(ps, 8);
                if (lr == 0) scr[row * 8 + w] = ps;
            }
        __syncthreads();
        // pass 4: mu3 ; u sumsq
#pragma unroll
        for (int i = 0; i < 5; ++i)
#pragma unroll
            for (int r = 0; r < 4; ++r) {
                int row = i * 16 + lq * 4 + r;
                float s = 0.f;
#pragma unroll
                for (int q = 0; q < 8; ++q) s += scr[row * 8 + q];
                float mu = s * (1.f / 512.f);
                mus[i][r] = mu;
                float ps2 = 0.f;
#pragma unroll
                for (int j = 0; j < 4; ++j) { float d = acc[i][j][r] - mu; ps2 += d * d; }
                ps2 += __shfl_xor(ps2, 1); ps2 += __shfl_xor(ps2, 2);
                ps2 += __shfl_xor(ps2, 4); ps2 += __shfl_xor(ps2, 8);
                if (lr == 0) scr2[row * 8 + w] = ps2;
            }
        __syncthreads();
        // pass 5: out = LNF(u)
#pragma unroll
        for (int i = 0; i < 5; ++i)
#pragma unroll
            for (int r = 0; r < 4; ++r) {
                int row = i * 16 + lq * 4 + r;
                float s2 = 0.f;
#pragma unroll
                for (int q = 0; q < 8; ++q) s2 += scr2[row * 8 + q];
                float rstd = rsqrtf(s2 * (1.f / 512.f) + 1e-5f);
#pragma unroll
                for (int j = 0; j < 4; ++j) {
                    int col = w * 64 + j * 16 + lr;
                    out[(tok0 + row) * 512 + col] =
                        (acc[i][j][r] - mus[i][r]) * rstd * wfc[j] + bfc[j];
                }
            }
    }
}

// ---------------------------------------------------------------------------
extern "C" void kernel_launch(void* const* d_in, const int* in_sizes, int n_in,
                              void* d_out, int out_size, void* d_ws, size_t ws_size,
                              hipStream_t stream)
{
    const float* boxes = (const float*)d_in[0];
    const float* w_in  = (const float*)d_in[1];
    const float* b_in  = (const float*)d_in[2];
    const float* wqkv  = (const float*)d_in[3];
    const float* bqkv  = (const float*)d_in[4];
    const float* wo    = (const float*)d_in[5];
    const float* bo    = (const float*)d_in[6];
    const float* ln1w  = (const float*)d_in[7];
    const float* ln1b  = (const float*)d_in[8];
    const float* w1    = (const float*)d_in[9];
    const float* b1    = (const float*)d_in[10];
    const float* w2    = (const float*)d_in[11];
    const float* b2    = (const float*)d_in[12];
    const float* ln2w  = (const float*)d_in[13];
    const float* ln2b  = (const float*)d_in[14];
    const float* lnfw  = (const float*)d_in[15];
    const float* lnfb  = (const float*)d_in[16];
    float* out = (float*)d_out;

    char* ws = (char*)d_ws;
    bf*    At     = (bf*)(ws + 0);                            //  1,048,576
    bf*    Ct     = (bf*)(ws + 1048576);                      //  1,048,576
    bf*    W1b    = (bf*)(ws + 2097152);                      //  524,288
    bf*    W2b    = (bf*)(ws + 2621440);                      //  524,288
    float* wconst = (float*)(ws + 3145728);                   //  2,048
    float* uvec   = (float*)(ws + 3147776);                   //  4,096
    float* rel    = (float*)(ws + 3151872);                   //  13,107,200

    dim3 gblk(256);

    prep_folds<<<4097, gblk, 0, stream>>>(wqkv, bqkv, wo, bo, At, Ct, wconst, uvec);
    cvt_w<<<256, gblk, 0, stream>>>(w1, W1b);
    cvt_w<<<256, gblk, 0, stream>>>(w2, W2b);
    rel_kernel<<<(MTOT + 255) / 256, gblk, 0, stream>>>(boxes, rel);

    fused<<<MTOT / 80, 512, 0, stream>>>(rel, w_in, b_in, At, Ct, uvec, wconst,
                                         W1b, b1, W2b, b2,
                                         ln1w, ln1b, ln2w, ln2b, lnfw, lnfb, out);
}